// Round 1
// baseline (628.988 us; speedup 1.0000x reference)
//
#include <hip/hip_runtime.h>
#include <hip/hip_bf16.h>

#define GAS __attribute__((address_space(1)))
#define LAS __attribute__((address_space(3)))

typedef __bf16 bf16x8 __attribute__((ext_vector_type(8)));
typedef float f32x4 __attribute__((ext_vector_type(4)));

constexpr int Kd = 4096;   // IN features
constexpr int Nd = 4096;   // OUT features
constexpr int RANKd = 32;
constexpr int NGroups = 32;    // IN / 128
constexpr int BM = 128, BN = 128, BK = 32;

// ---------------------------------------------------------------------------
// Kernel 1: W_bf16[n][k] = (q[n][k]-8)*scales[n][k/128] + sum_r U[n][r]*V[r][k]
// Block = 256 threads, covers 4 n-rows x full K (thread: 16 consecutive k).
// ---------------------------------------------------------------------------
__global__ __launch_bounds__(256) void build_w(
    const int* __restrict__ q, const float* __restrict__ scales,
    const float* __restrict__ U, const float* __restrict__ V,
    __hip_bfloat16* __restrict__ W)
{
  const int t  = threadIdx.x;
  const int n0 = blockIdx.x * 4;
  const int k0 = t * 16;                 // 256*16 = 4096 = K

  __shared__ float u_s[4][RANKd];
  if (t < 4 * RANKd) u_s[t >> 5][t & 31] = U[(size_t)(n0 + (t >> 5)) * RANKd + (t & 31)];
  __syncthreads();

  float acc[4][16];
  #pragma unroll
  for (int nn = 0; nn < 4; ++nn) {
    const int4* q4 = (const int4*)(q + (size_t)(n0 + nn) * Kd + k0);
    const float sc = scales[(size_t)(n0 + nn) * NGroups + (k0 >> 7)];
    #pragma unroll
    for (int c = 0; c < 4; ++c) {
      int4 qq = q4[c];
      acc[nn][c*4+0] = (float)(qq.x - 8) * sc;
      acc[nn][c*4+1] = (float)(qq.y - 8) * sc;
      acc[nn][c*4+2] = (float)(qq.z - 8) * sc;
      acc[nn][c*4+3] = (float)(qq.w - 8) * sc;
    }
  }

  for (int r = 0; r < RANKd; ++r) {
    const float4* v4 = (const float4*)(V + (size_t)r * Kd + k0);
    float4 vv[4];
    #pragma unroll
    for (int c = 0; c < 4; ++c) vv[c] = v4[c];
    #pragma unroll
    for (int nn = 0; nn < 4; ++nn) {
      const float u = u_s[nn][r];
      #pragma unroll
      for (int c = 0; c < 4; ++c) {
        acc[nn][c*4+0] += u * vv[c].x;
        acc[nn][c*4+1] += u * vv[c].y;
        acc[nn][c*4+2] += u * vv[c].z;
        acc[nn][c*4+3] += u * vv[c].w;
      }
    }
  }

  #pragma unroll
  for (int nn = 0; nn < 4; ++nn) {
    union { __hip_bfloat16 h[16]; int4 v[2]; } uo;
    #pragma unroll
    for (int i = 0; i < 16; ++i) uo.h[i] = __float2bfloat16(acc[nn][i]);
    int4* dst = (int4*)(W + (size_t)(n0 + nn) * Kd + k0);
    dst[0] = uo.v[0];
    dst[1] = uo.v[1];
  }
}

// ---------------------------------------------------------------------------
// Kernel 2: x fp32 -> bf16 (8 elems/thread, 16B stores)
// ---------------------------------------------------------------------------
__global__ __launch_bounds__(256) void convert_x(
    const float* __restrict__ x, __hip_bfloat16* __restrict__ xb)
{
  const size_t i = ((size_t)blockIdx.x * 256 + threadIdx.x) * 8;
  float4 a = *(const float4*)(x + i);
  float4 b = *(const float4*)(x + i + 4);
  union { __hip_bfloat16 h[8]; int4 v; } u;
  u.h[0] = __float2bfloat16(a.x); u.h[1] = __float2bfloat16(a.y);
  u.h[2] = __float2bfloat16(a.z); u.h[3] = __float2bfloat16(a.w);
  u.h[4] = __float2bfloat16(b.x); u.h[5] = __float2bfloat16(b.y);
  u.h[6] = __float2bfloat16(b.z); u.h[7] = __float2bfloat16(b.w);
  *(int4*)(xb + i) = u.v;
}

// ---------------------------------------------------------------------------
// Kernel 3: C[m][n] = sum_k A[m][k]*W[n][k] + bias[n]
// m97 structure: 128x128 tile, BK=32, 4 waves (2x2), 16x16x32 bf16 MFMA 4x4
// per wave, global_load_lds width-16 staging, 2-barrier K loop.
// ABF16=false stages A from fp32 with in-register conversion (ws fallback).
// ---------------------------------------------------------------------------
template <bool ABF16>
__global__ __launch_bounds__(256) void gemm_bt(
    const void* __restrict__ Ap, const __hip_bfloat16* __restrict__ Bt,
    const float* __restrict__ bias, float* __restrict__ C)
{
  __shared__ __hip_bfloat16 As[BM * BK];   // 8 KB, row-major [m][k]
  __shared__ __hip_bfloat16 Bs[BN * BK];   // 8 KB, row-major [n][k]

  const int t  = threadIdx.x;
  const int l  = t & 63;
  const int w  = t >> 6;          // wave 0..3
  const int wm = w >> 1;          // wave m index (0..1)
  const int wn = w & 1;           // wave n index (0..1)
  const int bm0 = blockIdx.y * BM;
  const int bn0 = blockIdx.x * BN;

  f32x4 acc[4][4];
  #pragma unroll
  for (int i = 0; i < 4; ++i)
    #pragma unroll
    for (int j = 0; j < 4; ++j)
      acc[i][j] = (f32x4){0.f, 0.f, 0.f, 0.f};

  const __hip_bfloat16* Abf = (const __hip_bfloat16*)Ap;
  const float*          A32 = (const float*)Ap;

  // global_load_lds staging: one inst = 64 lanes x 16B = 1 KB contiguous LDS.
  // lane l covers row (w*16 + l/4 + 64*round), bytes (l&3)*16 of the 64B row.
  const __hip_bfloat16* ag0 = Abf + (size_t)(bm0 + w * 16 + (l >> 2)) * Kd + (l & 3) * 8;
  const __hip_bfloat16* bg0 = Bt  + (size_t)(bn0 + w * 16 + (l >> 2)) * Kd + (l & 3) * 8;
  char* asb = (char*)As + w * 1024;   // wave-uniform LDS base (HW adds lane*16)
  char* bsb = (char*)Bs + w * 1024;

  // fp32-A fallback staging addresses (thread: 16 floats of one row)
  const int arow = t >> 1;
  const int acol = (t & 1) * 16;
  const float* a32p = A32 + (size_t)(bm0 + arow) * Kd + acol;
  __hip_bfloat16* asw = As + arow * BK + acol;

  for (int kt = 0; kt < Kd / BK; ++kt) {
    if constexpr (ABF16) {
      const __hip_bfloat16* ag = ag0 + kt * BK;
      __builtin_amdgcn_global_load_lds((GAS void*)ag,            (LAS void*)asb,          16, 0, 0);
      __builtin_amdgcn_global_load_lds((GAS void*)(ag + 64*Kd),  (LAS void*)(asb + 4096), 16, 0, 0);
    } else {
      const float* ap = a32p + kt * BK;
      float4 f0 = ((const float4*)ap)[0];
      float4 f1 = ((const float4*)ap)[1];
      float4 f2 = ((const float4*)ap)[2];
      float4 f3 = ((const float4*)ap)[3];
      union { __hip_bfloat16 h[16]; int4 v[2]; } u;
      u.h[ 0]=__float2bfloat16(f0.x); u.h[ 1]=__float2bfloat16(f0.y);
      u.h[ 2]=__float2bfloat16(f0.z); u.h[ 3]=__float2bfloat16(f0.w);
      u.h[ 4]=__float2bfloat16(f1.x); u.h[ 5]=__float2bfloat16(f1.y);
      u.h[ 6]=__float2bfloat16(f1.z); u.h[ 7]=__float2bfloat16(f1.w);
      u.h[ 8]=__float2bfloat16(f2.x); u.h[ 9]=__float2bfloat16(f2.y);
      u.h[10]=__float2bfloat16(f2.z); u.h[11]=__float2bfloat16(f2.w);
      u.h[12]=__float2bfloat16(f3.x); u.h[13]=__float2bfloat16(f3.y);
      u.h[14]=__float2bfloat16(f3.z); u.h[15]=__float2bfloat16(f3.w);
      ((int4*)asw)[0] = u.v[0];
      ((int4*)asw)[1] = u.v[1];
    }
    {
      const __hip_bfloat16* bg = bg0 + kt * BK;
      __builtin_amdgcn_global_load_lds((GAS void*)bg,            (LAS void*)bsb,          16, 0, 0);
      __builtin_amdgcn_global_load_lds((GAS void*)(bg + 64*Kd),  (LAS void*)(bsb + 4096), 16, 0, 0);
    }

    __syncthreads();   // drains vmcnt/lgkmcnt before compute

    bf16x8 af[4], bf[4];
    #pragma unroll
    for (int i = 0; i < 4; ++i)
      af[i] = *(const bf16x8*)((const char*)As + (wm*64 + i*16 + (l & 15)) * 64 + (l >> 4) * 16);
    #pragma unroll
    for (int j = 0; j < 4; ++j)
      bf[j] = *(const bf16x8*)((const char*)Bs + (wn*64 + j*16 + (l & 15)) * 64 + (l >> 4) * 16);

    #pragma unroll
    for (int i = 0; i < 4; ++i)
      #pragma unroll
      for (int j = 0; j < 4; ++j)
        acc[i][j] = __builtin_amdgcn_mfma_f32_16x16x32_bf16(af[i], bf[j], acc[i][j], 0, 0, 0);

    __syncthreads();   // LDS safe to overwrite
  }

  // Epilogue: C/D layout col=lane&15, row=(lane>>4)*4+reg. Fuse bias.
  const int colbase = bn0 + wn * 64 + (l & 15);
  const int rowbase = bm0 + wm * 64 + (l >> 4) * 4;
  #pragma unroll
  for (int j = 0; j < 4; ++j) {
    const int col = colbase + j * 16;
    const float bz = bias[col];
    #pragma unroll
    for (int i = 0; i < 4; ++i) {
      const int row0 = rowbase + i * 16;
      #pragma unroll
      for (int r = 0; r < 4; ++r)
        C[(size_t)(row0 + r) * Nd + col] = acc[i][j][r] + bz;
    }
  }
}

// ---------------------------------------------------------------------------
extern "C" void kernel_launch(void* const* d_in, const int* in_sizes, int n_in,
                              void* d_out, int out_size, void* d_ws, size_t ws_size,
                              hipStream_t stream)
{
  const float* x      = (const float*)d_in[0];
  const int*   q      = (const int*)  d_in[1];
  const float* scales = (const float*)d_in[2];
  const float* U      = (const float*)d_in[3];
  const float* V      = (const float*)d_in[4];
  const float* bias   = (const float*)d_in[5];
  float* out = (float*)d_out;

  const int M = in_sizes[0] / Kd;   // B*S = 8192

  __hip_bfloat16* Wb = (__hip_bfloat16*)d_ws;
  const size_t wbytes = (size_t)Nd * Kd * sizeof(__hip_bfloat16);  // 33.5 MB
  const size_t xbytes = (size_t)M  * Kd * sizeof(__hip_bfloat16);  // 67 MB

  build_w<<<dim3(Nd / 4), dim3(256), 0, stream>>>(q, scales, U, V, Wb);

  dim3 grid(Nd / BN, M / BM);
  if (ws_size >= wbytes + xbytes) {
    __hip_bfloat16* Xb = (__hip_bfloat16*)((char*)d_ws + wbytes);
    const int nconv = (M * (Kd / 8)) / 256;
    convert_x<<<dim3(nconv), dim3(256), 0, stream>>>(x, Xb);
    gemm_bt<true><<<grid, dim3(256), 0, stream>>>((const void*)Xb, Wb, bias, out);
  } else {
    gemm_bt<false><<<grid, dim3(256), 0, stream>>>((const void*)x, Wb, bias, out);
  }
}

// Round 2
// 604.427 us; speedup vs baseline: 1.0406x; 1.0406x over previous
//
#include <hip/hip_runtime.h>
#include <hip/hip_bf16.h>

#define GAS __attribute__((address_space(1)))
#define LAS __attribute__((address_space(3)))

typedef __bf16 bf16x8 __attribute__((ext_vector_type(8)));
typedef float f32x4 __attribute__((ext_vector_type(4)));

constexpr int Kd = 4096;   // IN features
constexpr int Nd = 4096;   // OUT features
constexpr int RANKd = 32;
constexpr int NGroups = 32;    // IN / 128
constexpr int BM = 128, BN = 128, BK = 32;

// ---------------------------------------------------------------------------
// Kernel 1 v2: W_bf16[n][k] = (q-8)*scale + U@V, LDS-staged U and V tiles.
// Block = 256 threads covers 32 rows x 256 k-cols; thread = 4 rows x 8 cols.
// V traffic: 2048 blocks x 32 KB = 64 MB (L3-hot) vs v1's 512 MB chained.
// ---------------------------------------------------------------------------
constexpr int BWR = 32;    // rows per block
constexpr int BWC = 256;   // k-cols per block

__global__ __launch_bounds__(256) void build_w(
    const int* __restrict__ q, const float* __restrict__ scales,
    const float* __restrict__ U, const float* __restrict__ V,
    __hip_bfloat16* __restrict__ W)
{
  __shared__ float V_s[RANKd][BWC + 4];    // padded: stride 260 floats (1040 B, 16B-aligned)
  __shared__ float U_s[BWR][RANKd + 1];

  const int t  = threadIdx.x;
  const int n0 = blockIdx.y * BWR;
  const int k0 = blockIdx.x * BWC;

  {  // stage U: 32x32 floats, 4 per thread
    const int idx = t * 4;
    const int row = idx >> 5, rr = idx & 31;
    float4 uv = *(const float4*)(U + (size_t)(n0 + row) * RANKd + rr);
    U_s[row][rr] = uv.x; U_s[row][rr + 1] = uv.y;
    U_s[row][rr + 2] = uv.z; U_s[row][rr + 3] = uv.w;
  }
  #pragma unroll
  for (int i = 0; i < 8; ++i) {  // stage V: 32x256 floats, 8 float4 per thread
    const int idx = i * 1024 + t * 4;
    const int vr = idx >> 8, vc = idx & 255;
    float4 vv = *(const float4*)(V + (size_t)vr * Kd + k0 + vc);
    *(float4*)&V_s[vr][vc] = vv;
  }
  __syncthreads();

  const int rs   = t >> 5;          // row slot 0..7
  const int cs   = t & 31;          // col slot 0..31
  const int row0 = n0 + rs * 4;
  const int kc   = k0 + cs * 8;
  const int grp  = kc >> 7;

  float acc[4][8];
  #pragma unroll
  for (int j = 0; j < 4; ++j) {
    const int4* q4 = (const int4*)(q + (size_t)(row0 + j) * Kd + kc);
    int4 a = q4[0], b = q4[1];
    const float sc = scales[(size_t)(row0 + j) * NGroups + grp];
    acc[j][0] = (float)(a.x - 8) * sc; acc[j][1] = (float)(a.y - 8) * sc;
    acc[j][2] = (float)(a.z - 8) * sc; acc[j][3] = (float)(a.w - 8) * sc;
    acc[j][4] = (float)(b.x - 8) * sc; acc[j][5] = (float)(b.y - 8) * sc;
    acc[j][6] = (float)(b.z - 8) * sc; acc[j][7] = (float)(b.w - 8) * sc;
  }

  #pragma unroll 4
  for (int r = 0; r < RANKd; ++r) {
    float4 v0 = *(const float4*)&V_s[r][cs * 8];
    float4 v1 = *(const float4*)&V_s[r][cs * 8 + 4];
    #pragma unroll
    for (int j = 0; j < 4; ++j) {
      const float u = U_s[rs * 4 + j][r];
      acc[j][0] += u * v0.x; acc[j][1] += u * v0.y;
      acc[j][2] += u * v0.z; acc[j][3] += u * v0.w;
      acc[j][4] += u * v1.x; acc[j][5] += u * v1.y;
      acc[j][6] += u * v1.z; acc[j][7] += u * v1.w;
    }
  }

  #pragma unroll
  for (int j = 0; j < 4; ++j) {
    union { __hip_bfloat16 h[8]; int4 v; } o;
    #pragma unroll
    for (int i = 0; i < 8; ++i) o.h[i] = __float2bfloat16(acc[j][i]);
    *(int4*)(W + (size_t)(row0 + j) * Kd + kc) = o.v;
  }
}

// ---------------------------------------------------------------------------
// Kernel 2: x fp32 -> bf16 (8 elems/thread, 16B stores)
// ---------------------------------------------------------------------------
__global__ __launch_bounds__(256) void convert_x(
    const float* __restrict__ x, __hip_bfloat16* __restrict__ xb)
{
  const size_t i = ((size_t)blockIdx.x * 256 + threadIdx.x) * 8;
  float4 a = *(const float4*)(x + i);
  float4 b = *(const float4*)(x + i + 4);
  union { __hip_bfloat16 h[8]; int4 v; } u;
  u.h[0] = __float2bfloat16(a.x); u.h[1] = __float2bfloat16(a.y);
  u.h[2] = __float2bfloat16(a.z); u.h[3] = __float2bfloat16(a.w);
  u.h[4] = __float2bfloat16(b.x); u.h[5] = __float2bfloat16(b.y);
  u.h[6] = __float2bfloat16(b.z); u.h[7] = __float2bfloat16(b.w);
  *(int4*)(xb + i) = u.v;
}

// ---------------------------------------------------------------------------
// Kernel 3: C[m][n] = sum_k A[m][k]*W[n][k] + bias[n]
// m97 structure + XOR-swizzled LDS tiles to kill ds_read_b128 bank conflicts.
// LDS layout: addr(r, c) = r*64 + (c ^ ((r>>1)&3))*16 bytes  (c = 16B k-chunk).
//  - staging (global_load_lds, lane l -> LDS flat l): lane loads global chunk
//    c = (l&3) ^ ((l>>3)&3); permutation stays within each row's 64B, so the
//    wave still covers contiguous 1KB -> coalescing preserved.
//  - fragment read: chunk (l>>4) read at ((l>>4) ^ ((l>>1)&3))*16; per 8-lane
//    phase all 8 bank-groups distinct -> conflict-free.
// ---------------------------------------------------------------------------
template <bool ABF16>
__global__ __launch_bounds__(256) void gemm_bt(
    const void* __restrict__ Ap, const __hip_bfloat16* __restrict__ Bt,
    const float* __restrict__ bias, float* __restrict__ C)
{
  __shared__ __hip_bfloat16 As[BM * BK];   // 8 KB
  __shared__ __hip_bfloat16 Bs[BN * BK];   // 8 KB

  const int t  = threadIdx.x;
  const int l  = t & 63;
  const int w  = t >> 6;
  const int wm = w >> 1;
  const int wn = w & 1;
  const int bm0 = blockIdx.y * BM;
  const int bn0 = blockIdx.x * BN;

  f32x4 acc[4][4];
  #pragma unroll
  for (int i = 0; i < 4; ++i)
    #pragma unroll
    for (int j = 0; j < 4; ++j)
      acc[i][j] = (f32x4){0.f, 0.f, 0.f, 0.f};

  const __hip_bfloat16* Abf = (const __hip_bfloat16*)Ap;
  const float*          A32 = (const float*)Ap;

  // --- staging addresses (swizzled chunk within row) ---
  const int srow  = w * 16 + (l >> 2);                 // tile row, inst 1
  const int schnk = (l & 3) ^ ((l >> 3) & 3);          // swizzled 16B k-chunk
  const __hip_bfloat16* ag0 = Abf + (size_t)(bm0 + srow) * Kd + schnk * 8;
  const __hip_bfloat16* bg0 = Bt  + (size_t)(bn0 + srow) * Kd + schnk * 8;
  char* asb = (char*)As + w * 1024;
  char* bsb = (char*)Bs + w * 1024;

  // --- fp32-A fallback staging (row-major thread mapping, swizzled LDS write)
  const int arow = t >> 1;
  const int apair = (t & 1);                            // chunks {0,1} or {2,3}
  const float* a32p = A32 + (size_t)(bm0 + arow) * Kd + apair * 16;
  const int aswz = (arow >> 1) & 3;
  __hip_bfloat16* asw0 = As + arow * BK + (((apair * 2 + 0) ^ aswz) * 8);
  __hip_bfloat16* asw1 = As + arow * BK + (((apair * 2 + 1) ^ aswz) * 8);

  // --- fragment read offsets (swizzled) ---
  const int rlow = l & 15;
  const int rd_a = (wm * 64 + rlow) * 64 + (((l >> 4) ^ ((l >> 1) & 3)) * 16);
  const int rd_b = (wn * 64 + rlow) * 64 + (((l >> 4) ^ ((l >> 1) & 3)) * 16);

  for (int kt = 0; kt < Kd / BK; ++kt) {
    if constexpr (ABF16) {
      const __hip_bfloat16* ag = ag0 + kt * BK;
      __builtin_amdgcn_global_load_lds((GAS void*)ag,           (LAS void*)asb,          16, 0, 0);
      __builtin_amdgcn_global_load_lds((GAS void*)(ag + 64*Kd), (LAS void*)(asb + 4096), 16, 0, 0);
    } else {
      const float* ap = a32p + kt * BK;
      float4 f0 = ((const float4*)ap)[0];
      float4 f1 = ((const float4*)ap)[1];
      union { __hip_bfloat16 h[8]; int4 v; } u0, u1;
      u0.h[0]=__float2bfloat16(f0.x); u0.h[1]=__float2bfloat16(f0.y);
      u0.h[2]=__float2bfloat16(f0.z); u0.h[3]=__float2bfloat16(f0.w);
      u1.h[0]=__float2bfloat16(f1.x); u1.h[1]=__float2bfloat16(f1.y);
      u1.h[2]=__float2bfloat16(f1.z); u1.h[3]=__float2bfloat16(f1.w);
      *(int4*)asw0 = u0.v;
      *(int4*)asw1 = u1.v;
    }
    {
      const __hip_bfloat16* bg = bg0 + kt * BK;
      __builtin_amdgcn_global_load_lds((GAS void*)bg,           (LAS void*)bsb,          16, 0, 0);
      __builtin_amdgcn_global_load_lds((GAS void*)(bg + 64*Kd), (LAS void*)(bsb + 4096), 16, 0, 0);
    }

    __syncthreads();

    bf16x8 af[4], bf[4];
    #pragma unroll
    for (int i = 0; i < 4; ++i)
      af[i] = *(const bf16x8*)((const char*)As + rd_a + i * 1024);
    #pragma unroll
    for (int j = 0; j < 4; ++j)
      bf[j] = *(const bf16x8*)((const char*)Bs + rd_b + j * 1024);

    #pragma unroll
    for (int i = 0; i < 4; ++i)
      #pragma unroll
      for (int j = 0; j < 4; ++j)
        acc[i][j] = __builtin_amdgcn_mfma_f32_16x16x32_bf16(af[i], bf[j], acc[i][j], 0, 0, 0);

    __syncthreads();
  }

  // Epilogue: C/D layout col=lane&15, row=(lane>>4)*4+reg; fuse bias.
  const int colbase = bn0 + wn * 64 + (l & 15);
  const int rowbase = bm0 + wm * 64 + (l >> 4) * 4;
  #pragma unroll
  for (int j = 0; j < 4; ++j) {
    const int col = colbase + j * 16;
    const float bz = bias[col];
    #pragma unroll
    for (int i = 0; i < 4; ++i) {
      const int row0 = rowbase + i * 16;
      #pragma unroll
      for (int r = 0; r < 4; ++r)
        C[(size_t)(row0 + r) * Nd + col] = acc[i][j][r] + bz;
    }
  }
}

// ---------------------------------------------------------------------------
extern "C" void kernel_launch(void* const* d_in, const int* in_sizes, int n_in,
                              void* d_out, int out_size, void* d_ws, size_t ws_size,
                              hipStream_t stream)
{
  const float* x      = (const float*)d_in[0];
  const int*   q      = (const int*)  d_in[1];
  const float* scales = (const float*)d_in[2];
  const float* U      = (const float*)d_in[3];
  const float* V      = (const float*)d_in[4];
  const float* bias   = (const float*)d_in[5];
  float* out = (float*)d_out;

  const int M = in_sizes[0] / Kd;   // B*S = 8192

  __hip_bfloat16* Wb = (__hip_bfloat16*)d_ws;
  const size_t wbytes = (size_t)Nd * Kd * sizeof(__hip_bfloat16);
  const size_t xbytes = (size_t)M  * Kd * sizeof(__hip_bfloat16);

  build_w<<<dim3(Kd / BWC, Nd / BWR), dim3(256), 0, stream>>>(q, scales, U, V, Wb);

  dim3 grid(Nd / BN, M / BM);
  if (ws_size >= wbytes + xbytes) {
    __hip_bfloat16* Xb = (__hip_bfloat16*)((char*)d_ws + wbytes);
    const int nconv = (M * (Kd / 8)) / 256;
    convert_x<<<dim3(nconv), dim3(256), 0, stream>>>(x, Xb);
    gemm_bt<true><<<grid, dim3(256), 0, stream>>>((const void*)Xb, Wb, bias, out);
  } else {
    gemm_bt<false><<<grid, dim3(256), 0, stream>>>((const void*)x, Wb, bias, out);
  }
}

// Round 3
// 581.267 us; speedup vs baseline: 1.0821x; 1.0398x over previous
//
#include <hip/hip_runtime.h>
#include <hip/hip_bf16.h>

#define GAS __attribute__((address_space(1)))
#define LAS __attribute__((address_space(3)))

typedef __bf16 bf16x8 __attribute__((ext_vector_type(8)));
typedef float f32x16 __attribute__((ext_vector_type(16)));

constexpr int Kd = 4096;   // IN
constexpr int Nd = 4096;   // OUT
constexpr int RANKd = 32;
constexpr int NG = 32;     // scale groups
constexpr int BM = 128, BN = 128, BK = 64;

// ---------------------------------------------------------------------------
// prep: fused W-build + x fp32->bf16 convert, split by block range.
//   blocks [0, NBUILD):        W[n][k] = (q-8)*scale + U@V   (LDS-staged U,V)
//   blocks [NBUILD, +nconv):   xb = bf16(x), 8192 elems/block
// V_s access: thread covers cols {cs*4..+3} and {128+cs*4..+3} -> 16B lane
// stride -> 4 words/bank (optimal), vs v2's 32B stride (8-deep).
// ---------------------------------------------------------------------------
constexpr int BWR = 32, BWC = 256;
constexpr int NBUILD = (Nd / BWR) * (Kd / BWC);   // 2048

__global__ __launch_bounds__(256) void prep(
    const int* __restrict__ q, const float* __restrict__ scales,
    const float* __restrict__ U, const float* __restrict__ V,
    __hip_bfloat16* __restrict__ W,
    const float* __restrict__ x, __hip_bfloat16* __restrict__ xb)
{
  __shared__ float V_s[RANKd][BWC + 4];
  __shared__ float U_s[BWR][RANKd + 1];

  const int t = threadIdx.x;
  const int bid = blockIdx.x;

  if (bid >= NBUILD) {   // ---- convert branch ----
    const size_t base = (size_t)(bid - NBUILD) * 8192;
    #pragma unroll
    for (int i = 0; i < 4; ++i) {
      const size_t idx = base + i * 2048 + t * 8;
      float4 a = *(const float4*)(x + idx);
      float4 b = *(const float4*)(x + idx + 4);
      union { __hip_bfloat16 h[8]; int4 v; } u;
      u.h[0] = __float2bfloat16(a.x); u.h[1] = __float2bfloat16(a.y);
      u.h[2] = __float2bfloat16(a.z); u.h[3] = __float2bfloat16(a.w);
      u.h[4] = __float2bfloat16(b.x); u.h[5] = __float2bfloat16(b.y);
      u.h[6] = __float2bfloat16(b.z); u.h[7] = __float2bfloat16(b.w);
      *(int4*)(xb + idx) = u.v;
    }
    return;
  }

  // ---- build branch ----
  const int bx = bid & 15;        // k-block (Kd/BWC = 16)
  const int by = bid >> 4;        // n-block
  const int n0 = by * BWR;
  const int k0 = bx * BWC;

  {  // stage U: 32x32 floats
    const int idx = t * 4;
    const int row = idx >> 5, rr = idx & 31;
    float4 uv = *(const float4*)(U + (size_t)(n0 + row) * RANKd + rr);
    U_s[row][rr] = uv.x; U_s[row][rr + 1] = uv.y;
    U_s[row][rr + 2] = uv.z; U_s[row][rr + 3] = uv.w;
  }
  #pragma unroll
  for (int i = 0; i < 8; ++i) {  // stage V: 32x256 floats
    const int idx = i * 1024 + t * 4;
    const int vr = idx >> 8, vc = idx & 255;
    *(float4*)&V_s[vr][vc] = *(const float4*)(V + (size_t)vr * Kd + k0 + vc);
  }
  __syncthreads();

  const int rs = t >> 5;            // row slot 0..7
  const int cs = t & 31;            // col slot 0..31
  const int row0 = n0 + rs * 4;
  const int c0 = cs * 4;            // local col set A
  const int c1 = 128 + cs * 4;      // local col set B
  const int g0 = k0 >> 7, g1 = g0 + 1;

  float acc[4][8];
  #pragma unroll
  for (int j = 0; j < 4; ++j) {
    const int* qr = q + (size_t)(row0 + j) * Kd + k0;
    int4 a = *(const int4*)(qr + c0);
    int4 b = *(const int4*)(qr + c1);
    const float s0 = scales[(size_t)(row0 + j) * NG + g0];
    const float s1 = scales[(size_t)(row0 + j) * NG + g1];
    acc[j][0] = (float)(a.x - 8) * s0; acc[j][1] = (float)(a.y - 8) * s0;
    acc[j][2] = (float)(a.z - 8) * s0; acc[j][3] = (float)(a.w - 8) * s0;
    acc[j][4] = (float)(b.x - 8) * s1; acc[j][5] = (float)(b.y - 8) * s1;
    acc[j][6] = (float)(b.z - 8) * s1; acc[j][7] = (float)(b.w - 8) * s1;
  }

  #pragma unroll 4
  for (int r = 0; r < RANKd; ++r) {
    float4 v0 = *(const float4*)&V_s[r][c0];
    float4 v1 = *(const float4*)&V_s[r][c1];
    #pragma unroll
    for (int j = 0; j < 4; ++j) {
      const float u = U_s[rs * 4 + j][r];
      acc[j][0] += u * v0.x; acc[j][1] += u * v0.y;
      acc[j][2] += u * v0.z; acc[j][3] += u * v0.w;
      acc[j][4] += u * v1.x; acc[j][5] += u * v1.y;
      acc[j][6] += u * v1.z; acc[j][7] += u * v1.w;
    }
  }

  #pragma unroll
  for (int j = 0; j < 4; ++j) {
    union { __hip_bfloat16 h[4]; uint2 v; } o0, o1;
    o0.h[0] = __float2bfloat16(acc[j][0]); o0.h[1] = __float2bfloat16(acc[j][1]);
    o0.h[2] = __float2bfloat16(acc[j][2]); o0.h[3] = __float2bfloat16(acc[j][3]);
    o1.h[0] = __float2bfloat16(acc[j][4]); o1.h[1] = __float2bfloat16(acc[j][5]);
    o1.h[2] = __float2bfloat16(acc[j][6]); o1.h[3] = __float2bfloat16(acc[j][7]);
    __hip_bfloat16* wr = W + (size_t)(row0 + j) * Kd + k0;
    *(uint2*)(wr + c0) = o0.v;
    *(uint2*)(wr + c1) = o1.v;
  }
}

// ---------------------------------------------------------------------------
// gemm: C[m][n] = sum_k A[m][k]*W[n][k] + bias[n]
// 128x128 tile, BK=64, 4 waves 2x2, wave = 64x64 via 2x2 of 32x32x16 MFMA.
// LDS rows are 128 B; swizzle addr(r,c)=r*128+((c^(r&7))*16) (c = 16B chunk):
//   reads land exactly 4 words/bank (b128 floor); staging permutes chunks
//   within each row so global_load_lds' 1KB/inst stays contiguous-coalesced.
// 32 MFMA per barrier-pair (vs 16 at BK=32) halves barrier-drain overhead.
// ---------------------------------------------------------------------------
template <bool ABF16>
__global__ __launch_bounds__(256) void gemm_bt(
    const void* __restrict__ Ap, const __hip_bfloat16* __restrict__ Bt,
    const float* __restrict__ bias, float* __restrict__ C)
{
  __shared__ __hip_bfloat16 As[BM * BK];   // 16 KB
  __shared__ __hip_bfloat16 Bs[BN * BK];   // 16 KB

  const int t  = threadIdx.x;
  const int l  = t & 63;
  const int w  = t >> 6;
  const int wm = w >> 1;
  const int wn = w & 1;
  const int bm0 = blockIdx.y * BM;
  const int bn0 = blockIdx.x * BN;

  f32x16 acc[2][2];
  #pragma unroll
  for (int i = 0; i < 2; ++i)
    #pragma unroll
    for (int j = 0; j < 2; ++j)
      acc[i][j] = (f32x16)(0.f);

  const __hip_bfloat16* Abf = (const __hip_bfloat16*)Ap;
  const float*          A32 = (const float*)Ap;

  // staging: inst covers 8 rows x 128 B; lane l -> row l>>3, LDS slot l&7,
  // which holds global chunk (l&7)^(l>>3).
  const int srow = l >> 3;
  const int schk = (l & 7) ^ srow;
  const __hip_bfloat16* ag0 = Abf + (size_t)(bm0 + w * 32 + srow) * Kd + schk * 8;
  const __hip_bfloat16* bg0 = Bt  + (size_t)(bn0 + w * 32 + srow) * Kd + schk * 8;
  char* asb = (char*)As + w * 32 * 128;
  char* bsb = (char*)Bs + w * 32 * 128;

  // fragment reads: lane l -> row rl=l&31, k-half kh=l>>5;
  // chunk c = ks*2+kh read at swizzled position (c ^ (rl&7)).
  const int rl = l & 31, kh = l >> 5, rx = rl & 7;
  const char* Ard = (const char*)As + (wm * 64 + rl) * 128;
  const char* Brd = (const char*)Bs + (wn * 64 + rl) * 128;

  // fp32-A fallback staging: thread t -> row t>>1, col-half (t&1)*32
  const int arow = t >> 1, ahalf = t & 1, arx = arow & 7;
  const float* a32p = A32 + (size_t)(bm0 + arow) * Kd + ahalf * 32;
  char* awr = (char*)As + arow * 128;

  for (int kt = 0; kt < Kd / BK; ++kt) {
    if constexpr (ABF16) {
      const __hip_bfloat16* ag = ag0 + kt * BK;
      #pragma unroll
      for (int s = 0; s < 4; ++s)
        __builtin_amdgcn_global_load_lds((GAS void*)(ag + s * 8 * Kd),
                                         (LAS void*)(asb + s * 1024), 16, 0, 0);
    } else {
      const float* ap = a32p + kt * BK;
      #pragma unroll
      for (int cc = 0; cc < 4; ++cc) {
        float4 f0 = ((const float4*)ap)[cc * 2];
        float4 f1 = ((const float4*)ap)[cc * 2 + 1];
        union { __hip_bfloat16 h[8]; int4 v; } u;
        u.h[0] = __float2bfloat16(f0.x); u.h[1] = __float2bfloat16(f0.y);
        u.h[2] = __float2bfloat16(f0.z); u.h[3] = __float2bfloat16(f0.w);
        u.h[4] = __float2bfloat16(f1.x); u.h[5] = __float2bfloat16(f1.y);
        u.h[6] = __float2bfloat16(f1.z); u.h[7] = __float2bfloat16(f1.w);
        const int c = ahalf * 4 + cc;
        *(int4*)(awr + ((c ^ arx) * 16)) = u.v;
      }
    }
    {
      const __hip_bfloat16* bg = bg0 + kt * BK;
      #pragma unroll
      for (int s = 0; s < 4; ++s)
        __builtin_amdgcn_global_load_lds((GAS void*)(bg + s * 8 * Kd),
                                         (LAS void*)(bsb + s * 1024), 16, 0, 0);
    }

    __syncthreads();

    bf16x8 af[2][4], bfr[2][4];
    #pragma unroll
    for (int mi = 0; mi < 2; ++mi)
      #pragma unroll
      for (int ks = 0; ks < 4; ++ks)
        af[mi][ks] = *(const bf16x8*)(Ard + mi * 4096 + (((ks * 2 + kh) ^ rx) * 16));
    #pragma unroll
    for (int nj = 0; nj < 2; ++nj)
      #pragma unroll
      for (int ks = 0; ks < 4; ++ks)
        bfr[nj][ks] = *(const bf16x8*)(Brd + nj * 4096 + (((ks * 2 + kh) ^ rx) * 16));

    #pragma unroll
    for (int ks = 0; ks < 4; ++ks)
      #pragma unroll
      for (int mi = 0; mi < 2; ++mi)
        #pragma unroll
        for (int nj = 0; nj < 2; ++nj)
          acc[mi][nj] = __builtin_amdgcn_mfma_f32_32x32x16_bf16(
              af[mi][ks], bfr[nj][ks], acc[mi][nj], 0, 0, 0);

    __syncthreads();
  }

  // Epilogue: 32x32 C/D layout col=lane&31, row=(reg&3)+8*(reg>>2)+4*(lane>>5)
  #pragma unroll
  for (int nj = 0; nj < 2; ++nj) {
    const int col = bn0 + wn * 64 + nj * 32 + rl;
    const float bz = bias[col];
    #pragma unroll
    for (int mi = 0; mi < 2; ++mi) {
      const int rbase = bm0 + wm * 64 + mi * 32 + 4 * kh;
      #pragma unroll
      for (int reg = 0; reg < 16; ++reg) {
        const int row = rbase + (reg & 3) + 8 * (reg >> 2);
        C[(size_t)row * Nd + col] = acc[mi][nj][reg] + bz;
      }
    }
  }
}

// ---------------------------------------------------------------------------
extern "C" void kernel_launch(void* const* d_in, const int* in_sizes, int n_in,
                              void* d_out, int out_size, void* d_ws, size_t ws_size,
                              hipStream_t stream)
{
  const float* x      = (const float*)d_in[0];
  const int*   q      = (const int*)  d_in[1];
  const float* scales = (const float*)d_in[2];
  const float* U      = (const float*)d_in[3];
  const float* V      = (const float*)d_in[4];
  const float* bias   = (const float*)d_in[5];
  float* out = (float*)d_out;

  const int M = in_sizes[0] / Kd;   // B*S = 8192

  __hip_bfloat16* Wb = (__hip_bfloat16*)d_ws;
  const size_t wbytes = (size_t)Nd * Kd * sizeof(__hip_bfloat16);
  const size_t xbytes = (size_t)M  * Kd * sizeof(__hip_bfloat16);

  dim3 grid(Nd / BN, M / BM);
  if (ws_size >= wbytes + xbytes) {
    __hip_bfloat16* Xb = (__hip_bfloat16*)((char*)d_ws + wbytes);
    const int nconv = (int)(((size_t)M * Kd) / 8192);
    prep<<<dim3(NBUILD + nconv), dim3(256), 0, stream>>>(q, scales, U, V, Wb, x, Xb);
    gemm_bt<true><<<grid, dim3(256), 0, stream>>>((const void*)Xb, Wb, bias, out);
  } else {
    prep<<<dim3(NBUILD), dim3(256), 0, stream>>>(q, scales, U, V, Wb, x, nullptr);
    gemm_bt<false><<<grid, dim3(256), 0, stream>>>((const void*)x, Wb, bias, out);
  }
}

// Round 4
// 573.610 us; speedup vs baseline: 1.0965x; 1.0133x over previous
//
#include <hip/hip_runtime.h>
#include <hip/hip_bf16.h>

#define GAS __attribute__((address_space(1)))
#define LAS __attribute__((address_space(3)))

typedef __bf16 bf16x8 __attribute__((ext_vector_type(8)));
typedef float f32x16 __attribute__((ext_vector_type(16)));

constexpr int Kd = 4096;   // IN
constexpr int Nd = 4096;   // OUT
constexpr int RANKd = 32;
constexpr int NG = 32;     // scale groups
constexpr int BM = 128, BN = 128, BK = 64;

// ---------------------------------------------------------------------------
// prep: fused W-build + x fp32->bf16 convert (unchanged from round 3).
// ---------------------------------------------------------------------------
constexpr int BWR = 32, BWC = 256;
constexpr int NBUILD = (Nd / BWR) * (Kd / BWC);   // 2048

__global__ __launch_bounds__(256) void prep(
    const int* __restrict__ q, const float* __restrict__ scales,
    const float* __restrict__ U, const float* __restrict__ V,
    __hip_bfloat16* __restrict__ W,
    const float* __restrict__ x, __hip_bfloat16* __restrict__ xb)
{
  __shared__ float V_s[RANKd][BWC + 4];
  __shared__ float U_s[BWR][RANKd + 1];

  const int t = threadIdx.x;
  const int bid = blockIdx.x;

  if (bid >= NBUILD) {   // ---- convert branch ----
    const size_t base = (size_t)(bid - NBUILD) * 8192;
    #pragma unroll
    for (int i = 0; i < 4; ++i) {
      const size_t idx = base + i * 2048 + t * 8;
      float4 a = *(const float4*)(x + idx);
      float4 b = *(const float4*)(x + idx + 4);
      union { __hip_bfloat16 h[8]; int4 v; } u;
      u.h[0] = __float2bfloat16(a.x); u.h[1] = __float2bfloat16(a.y);
      u.h[2] = __float2bfloat16(a.z); u.h[3] = __float2bfloat16(a.w);
      u.h[4] = __float2bfloat16(b.x); u.h[5] = __float2bfloat16(b.y);
      u.h[6] = __float2bfloat16(b.z); u.h[7] = __float2bfloat16(b.w);
      *(int4*)(xb + idx) = u.v;
    }
    return;
  }

  // ---- build branch ----
  const int bx = bid & 15;
  const int by = bid >> 4;
  const int n0 = by * BWR;
  const int k0 = bx * BWC;

  {  // stage U: 32x32 floats
    const int idx = t * 4;
    const int row = idx >> 5, rr = idx & 31;
    float4 uv = *(const float4*)(U + (size_t)(n0 + row) * RANKd + rr);
    U_s[row][rr] = uv.x; U_s[row][rr + 1] = uv.y;
    U_s[row][rr + 2] = uv.z; U_s[row][rr + 3] = uv.w;
  }
  #pragma unroll
  for (int i = 0; i < 8; ++i) {  // stage V: 32x256 floats
    const int idx = i * 1024 + t * 4;
    const int vr = idx >> 8, vc = idx & 255;
    *(float4*)&V_s[vr][vc] = *(const float4*)(V + (size_t)vr * Kd + k0 + vc);
  }
  __syncthreads();

  const int rs = t >> 5;
  const int cs = t & 31;
  const int row0 = n0 + rs * 4;
  const int c0 = cs * 4;
  const int c1 = 128 + cs * 4;
  const int g0 = k0 >> 7, g1 = g0 + 1;

  float acc[4][8];
  #pragma unroll
  for (int j = 0; j < 4; ++j) {
    const int* qr = q + (size_t)(row0 + j) * Kd + k0;
    int4 a = *(const int4*)(qr + c0);
    int4 b = *(const int4*)(qr + c1);
    const float s0 = scales[(size_t)(row0 + j) * NG + g0];
    const float s1 = scales[(size_t)(row0 + j) * NG + g1];
    acc[j][0] = (float)(a.x - 8) * s0; acc[j][1] = (float)(a.y - 8) * s0;
    acc[j][2] = (float)(a.z - 8) * s0; acc[j][3] = (float)(a.w - 8) * s0;
    acc[j][4] = (float)(b.x - 8) * s1; acc[j][5] = (float)(b.y - 8) * s1;
    acc[j][6] = (float)(b.z - 8) * s1; acc[j][7] = (float)(b.w - 8) * s1;
  }

  #pragma unroll 4
  for (int r = 0; r < RANKd; ++r) {
    float4 v0 = *(const float4*)&V_s[r][c0];
    float4 v1 = *(const float4*)&V_s[r][c1];
    #pragma unroll
    for (int j = 0; j < 4; ++j) {
      const float u = U_s[rs * 4 + j][r];
      acc[j][0] += u * v0.x; acc[j][1] += u * v0.y;
      acc[j][2] += u * v0.z; acc[j][3] += u * v0.w;
      acc[j][4] += u * v1.x; acc[j][5] += u * v1.y;
      acc[j][6] += u * v1.z; acc[j][7] += u * v1.w;
    }
  }

  #pragma unroll
  for (int j = 0; j < 4; ++j) {
    union { __hip_bfloat16 h[4]; uint2 v; } o0, o1;
    o0.h[0] = __float2bfloat16(acc[j][0]); o0.h[1] = __float2bfloat16(acc[j][1]);
    o0.h[2] = __float2bfloat16(acc[j][2]); o0.h[3] = __float2bfloat16(acc[j][3]);
    o1.h[0] = __float2bfloat16(acc[j][4]); o1.h[1] = __float2bfloat16(acc[j][5]);
    o1.h[2] = __float2bfloat16(acc[j][6]); o1.h[3] = __float2bfloat16(acc[j][7]);
    __hip_bfloat16* wr = W + (size_t)(row0 + j) * Kd + k0;
    *(uint2*)(wr + c0) = o0.v;
    *(uint2*)(wr + c1) = o1.v;
  }
}

// ---------------------------------------------------------------------------
// gemm: 128x128 tile, BK=64, 32x32x16 MFMA 2x2/wave — round-3 structure with
// DUAL-SLAB LDS: tile stored as 2 slabs of (128 rows x 64B), slab h = k-half.
// Within a slab: addr(r, c) = r*64 + ((c ^ ((r>>1)&3)) * 16)  [round-2-proven
// conflict-free geometry: per 8 lanes, 8 distinct 16B positions ALTERNATING
// 64B bank-halves]. Staging permutes 16B chunks within each row: coalescing
// of the 1KB global_load_lds window is preserved.
// ---------------------------------------------------------------------------
template <bool ABF16>
__global__ __launch_bounds__(256) void gemm_bt(
    const void* __restrict__ Ap, const __hip_bfloat16* __restrict__ Bt,
    const float* __restrict__ bias, float* __restrict__ C)
{
  __shared__ __hip_bfloat16 As[BM * BK];   // 16 KB = 2 slabs x 8 KB
  __shared__ __hip_bfloat16 Bs[BN * BK];   // 16 KB

  const int t  = threadIdx.x;
  const int l  = t & 63;
  const int w  = t >> 6;
  const int wm = w >> 1;
  const int wn = w & 1;
  const int bm0 = blockIdx.y * BM;
  const int bn0 = blockIdx.x * BN;

  f32x16 acc[2][2];
  #pragma unroll
  for (int i = 0; i < 2; ++i)
    #pragma unroll
    for (int j = 0; j < 2; ++j)
      acc[i][j] = (f32x16)(0.f);

  const __hip_bfloat16* Abf = (const __hip_bfloat16*)Ap;
  const float*          A32 = (const float*)Ap;

  // staging: one inst = 16 rows x 64B (one slab). lane l -> row l>>2,
  // LDS slot l&3 holds global chunk (l&3)^((l>>3)&3)  [(l>>3)&3 = (row>>1)&3]
  const int sr   = l >> 2;
  const int schk = (l & 3) ^ ((l >> 3) & 3);
  const __hip_bfloat16* ag0 = Abf + (size_t)(bm0 + w * 32 + sr) * Kd + schk * 8;
  const __hip_bfloat16* bg0 = Bt  + (size_t)(bn0 + w * 32 + sr) * Kd + schk * 8;
  char* asb = (char*)As + w * 2048;   // slab 0; slab 1 at +8192
  char* bsb = (char*)Bs + w * 2048;

  // fragment reads: lane l -> row rl = l&31, k-half-of-16 kh = l>>5.
  // For ks: slab = ks>>1, chunk q = (ks&1)*2 + kh, at swizzled slot q^swz.
  const int rl = l & 31, kh = l >> 5, swz = (rl >> 1) & 3;
  const char* Ard = (const char*)As + (wm * 64 + rl) * 64;
  const char* Brd = (const char*)Bs + (wn * 64 + rl) * 64;

  // fp32-A fallback: thread t -> row t>>1, slab t&1 (k-half), 4 chunks
  const int arow = t >> 1, aslab = t & 1, arx = (arow >> 1) & 3;
  const float* a32p = A32 + (size_t)(bm0 + arow) * Kd + aslab * 32;
  char* awr = (char*)As + aslab * 8192 + arow * 64;

  for (int kt = 0; kt < Kd / BK; ++kt) {
    if constexpr (ABF16) {
      const __hip_bfloat16* ag = ag0 + kt * BK;
      __builtin_amdgcn_global_load_lds((GAS void*)ag,               (LAS void*)asb,                16, 0, 0);
      __builtin_amdgcn_global_load_lds((GAS void*)(ag + 16 * Kd),   (LAS void*)(asb + 1024),       16, 0, 0);
      __builtin_amdgcn_global_load_lds((GAS void*)(ag + 32),        (LAS void*)(asb + 8192),       16, 0, 0);
      __builtin_amdgcn_global_load_lds((GAS void*)(ag + 16*Kd + 32),(LAS void*)(asb + 8192 + 1024),16, 0, 0);
    } else {
      const float* ap = a32p + kt * BK;
      #pragma unroll
      for (int cc = 0; cc < 4; ++cc) {
        float4 f0 = ((const float4*)ap)[cc * 2];
        float4 f1 = ((const float4*)ap)[cc * 2 + 1];
        union { __hip_bfloat16 h[8]; int4 v; } u;
        u.h[0] = __float2bfloat16(f0.x); u.h[1] = __float2bfloat16(f0.y);
        u.h[2] = __float2bfloat16(f0.z); u.h[3] = __float2bfloat16(f0.w);
        u.h[4] = __float2bfloat16(f1.x); u.h[5] = __float2bfloat16(f1.y);
        u.h[6] = __float2bfloat16(f1.z); u.h[7] = __float2bfloat16(f1.w);
        *(int4*)(awr + ((cc ^ arx) * 16)) = u.v;
      }
    }
    {
      const __hip_bfloat16* bg = bg0 + kt * BK;
      __builtin_amdgcn_global_load_lds((GAS void*)bg,               (LAS void*)bsb,                16, 0, 0);
      __builtin_amdgcn_global_load_lds((GAS void*)(bg + 16 * Kd),   (LAS void*)(bsb + 1024),       16, 0, 0);
      __builtin_amdgcn_global_load_lds((GAS void*)(bg + 32),        (LAS void*)(bsb + 8192),       16, 0, 0);
      __builtin_amdgcn_global_load_lds((GAS void*)(bg + 16*Kd + 32),(LAS void*)(bsb + 8192 + 1024),16, 0, 0);
    }

    __syncthreads();

    bf16x8 af[2][4], bfr[2][4];
    #pragma unroll
    for (int mi = 0; mi < 2; ++mi)
      #pragma unroll
      for (int ks = 0; ks < 4; ++ks)
        af[mi][ks] = *(const bf16x8*)(Ard + (ks >> 1) * 8192 + mi * 2048 +
                                      ((((ks & 1) * 2 + kh) ^ swz) * 16));
    #pragma unroll
    for (int nj = 0; nj < 2; ++nj)
      #pragma unroll
      for (int ks = 0; ks < 4; ++ks)
        bfr[nj][ks] = *(const bf16x8*)(Brd + (ks >> 1) * 8192 + nj * 2048 +
                                       ((((ks & 1) * 2 + kh) ^ swz) * 16));

    #pragma unroll
    for (int ks = 0; ks < 4; ++ks)
      #pragma unroll
      for (int mi = 0; mi < 2; ++mi)
        #pragma unroll
        for (int nj = 0; nj < 2; ++nj)
          acc[mi][nj] = __builtin_amdgcn_mfma_f32_32x32x16_bf16(
              af[mi][ks], bfr[nj][ks], acc[mi][nj], 0, 0, 0);

    __syncthreads();
  }

  // Epilogue: 32x32 C/D layout col=lane&31, row=(reg&3)+8*(reg>>2)+4*(lane>>5)
  #pragma unroll
  for (int nj = 0; nj < 2; ++nj) {
    const int col = bn0 + wn * 64 + nj * 32 + rl;
    const float bz = bias[col];
    #pragma unroll
    for (int mi = 0; mi < 2; ++mi) {
      const int rbase = bm0 + wm * 64 + mi * 32 + 4 * kh;
      #pragma unroll
      for (int reg = 0; reg < 16; ++reg) {
        const int row = rbase + (reg & 3) + 8 * (reg >> 2);
        C[(size_t)row * Nd + col] = acc[mi][nj][reg] + bz;
      }
    }
  }
}

// ---------------------------------------------------------------------------
extern "C" void kernel_launch(void* const* d_in, const int* in_sizes, int n_in,
                              void* d_out, int out_size, void* d_ws, size_t ws_size,
                              hipStream_t stream)
{
  const float* x      = (const float*)d_in[0];
  const int*   q      = (const int*)  d_in[1];
  const float* scales = (const float*)d_in[2];
  const float* U      = (const float*)d_in[3];
  const float* V      = (const float*)d_in[4];
  const float* bias   = (const float*)d_in[5];
  float* out = (float*)d_out;

  const int M = in_sizes[0] / Kd;   // B*S = 8192

  __hip_bfloat16* Wb = (__hip_bfloat16*)d_ws;
  const size_t wbytes = (size_t)Nd * Kd * sizeof(__hip_bfloat16);
  const size_t xbytes = (size_t)M  * Kd * sizeof(__hip_bfloat16);

  dim3 grid(Nd / BN, M / BM);
  if (ws_size >= wbytes + xbytes) {
    __hip_bfloat16* Xb = (__hip_bfloat16*)((char*)d_ws + wbytes);
    const int nconv = (int)(((size_t)M * Kd) / 8192);
    prep<<<dim3(NBUILD + nconv), dim3(256), 0, stream>>>(q, scales, U, V, Wb, x, Xb);
    gemm_bt<true><<<grid, dim3(256), 0, stream>>>((const void*)Xb, Wb, bias, out);
  } else {
    prep<<<dim3(NBUILD), dim3(256), 0, stream>>>(q, scales, U, V, Wb, x, nullptr);
    gemm_bt<false><<<grid, dim3(256), 0, stream>>>((const void*)x, Wb, bias, out);
  }
}